// Round 2
// baseline (287.028 us; speedup 1.0000x reference)
//
#include <hip/hip_runtime.h>
#include <hip/hip_bf16.h>

#define BN 4
#define CN 64
#define ON 64
#define HN 128
#define WN 128
#define HWN (HN*WN)
#define NT 9

#define C_W 70
#define R_MAX 6
#define RC (R_MAX*C_W)            // 420 dwords per channel plane
#define SX_DWORDS (CN*RC)         // 26880 dwords = 107520 B

typedef __attribute__((ext_vector_type(8))) short bf16x8;
typedef __attribute__((ext_vector_type(4))) float floatx4;

static __device__ __forceinline__ unsigned short f2bf(float f) {
    unsigned int u = __builtin_bit_cast(unsigned int, f);
    u += 0x7fffu + ((u >> 16) & 1u);   // RNE
    return (unsigned short)(u >> 16);
}

// XCD-aware swizzle for 1024 blocks: XCD k owns works [k*128, k*128+128)
// = 64 consecutive rows of one image (~2.1MB x slice < 4MB L2/XCD).
static __device__ __forceinline__ int swz_work(int b) {
    return ((b & 7) << 7) | (b >> 3);
}

// ---------------------------------------------------------------------------
// Tiny kernel: w_conv (O,C,3,3) f32 -> wbf[n][o][c] bf16 for MFMA B-frags.
// ---------------------------------------------------------------------------
__global__ __launch_bounds__(256) void wbf_kernel(
    const float* __restrict__ w_conv, unsigned short* __restrict__ wbf)
{
    int gid = blockIdx.x * 256 + threadIdx.x;
    if (gid < ON*CN*NT) {
        int o   = gid / (CN*NT);
        int rem = gid - o*(CN*NT);
        int c   = rem / NT;
        int n   = rem - c*NT;
        wbf[(n*ON + o)*CN + c] = f2bf(w_conv[gid]);
    }
}

// ---------------------------------------------------------------------------
// Fused kernel: per 64-pixel block —
//   1) 3x3x64c conv from global (L2)  -> lie weight -> Hom -> 9 offsets (LDS)
//   2) taps: pair-base (by,bx in [0,126]) + 4 slot weights (clamp folded in)
//   3) exact bounding box via shared atomics; stage window [64][R][C_W] f32
//   4) 9 phases: bilinear gather FROM LDS -> bf16 sT tile -> MFMA vs wbf
// Block-uniform global-gather fallback if window exceeds 6x70 (correctness).
// ---------------------------------------------------------------------------
__global__ __launch_bounds__(256) void fused_deform(
    const float* __restrict__ x, const float* __restrict__ w_off,
    const float* __restrict__ P, const float* __restrict__ d,
    const float* __restrict__ Pinv,
    const unsigned short* __restrict__ wbf, float* __restrict__ out)
{
    __shared__ __align__(16) char lds[128320];
    float*          sx    = (float*)lds;                      // [64][6][70] f32 (staged window)
    int*            tapP  = (int*)(lds + 107520);             // [576] by*256+bx
    float4*         tapW  = (float4*)(lds + 109824);          // [576]
    unsigned short* sT    = (unsigned short*)(lds + 119040);  // [64][72] bf16 (gather phase)
    // overlays inside sT region (dead until gather phase):
    float*  swoff = (float*)(lds + 119040);                   // [576] w_off
    float*  sred  = (float*)(lds + 121344);                   // [4][64]
    float2* sOffs = (float2*)(lds + 122368);                  // [64][9]
    int*    sB    = (int*)(lds + 126976);                     // bounds minby,maxby,minbx,maxbx

    const int tid = threadIdx.x;
    for (int i = tid; i < CN*NT; i += 256) swoff[i] = w_off[i];
    if (tid == 0) { sB[0] = HN-1; sB[1] = 0; sB[2] = WN-1; sB[3] = 0; }

    const int work  = swz_work(blockIdx.x);
    const int pbase = work << 6;
    const int w0    = pbase & (WN-1);
    const int hi    = (pbase >> 7) & (HN-1);
    const int bi    = pbase >> 14;
    const float* xb = x + (size_t)bi * CN * HWN;

    __syncthreads();                              // swoff + sB ready

    // ---- phase 1: lie-weight conv (thread = pixel x channel-group)
    {
        const int pix = tid & 63;
        const int cg  = tid >> 6;
        const int wi  = w0 + pix;
        const float* xc   = xb + (size_t)(cg*16)*HWN;
        const float* swc0 = &swoff[cg*16*NT];
        float accv = 0.f;
        #pragma unroll
        for (int ky = 0; ky < 3; ++ky) {
            int yy = hi + ky - 1;
            #pragma unroll
            for (int kx = 0; kx < 3; ++kx) {
                int xx = wi + kx - 1;
                bool v  = (yy >= 0) && (yy < HN) && (xx >= 0) && (xx < WN);
                float m = v ? 1.f : 0.f;
                int a   = v ? (yy*WN + xx) : 0;
                const float* swc = swc0 + (ky*3 + kx);
                float t0 = 0.f, t1 = 0.f, t2 = 0.f, t3 = 0.f;
                #pragma unroll
                for (int c = 0; c < 16; c += 4) {
                    t0 = fmaf(xc[(size_t)(c+0)*HWN + a], swc[(c+0)*NT], t0);
                    t1 = fmaf(xc[(size_t)(c+1)*HWN + a], swc[(c+1)*NT], t1);
                    t2 = fmaf(xc[(size_t)(c+2)*HWN + a], swc[(c+2)*NT], t2);
                    t3 = fmaf(xc[(size_t)(c+3)*HWN + a], swc[(c+3)*NT], t3);
                }
                accv = fmaf(m, (t0+t1)+(t2+t3), accv);
            }
        }
        sred[cg*64 + pix] = accv;
    }
    __syncthreads();

    // ---- phase 2: homography -> 9 offsets per pixel (64 threads)
    if (tid < 64) {
        float raw = (sred[0*64+tid]+sred[1*64+tid]) + (sred[2*64+tid]+sred[3*64+tid]);
        float lw  = fminf(fmaxf(raw + 0.5f, 0.f), 1.f);
        float pw[3];
        #pragma unroll
        for (int k = 0; k < 3; ++k) pw[k] = exp2f(lw * log2f(d[k]));
        float Hm[9];
        #pragma unroll
        for (int i = 0; i < 3; ++i)
            #pragma unroll
            for (int j = 0; j < 3; ++j)
                Hm[i*3+j] = P[i*3+0]*pw[0]*Pinv[0+j]
                          + P[i*3+1]*pw[1]*Pinv[3+j]
                          + P[i*3+2]*pw[2]*Pinv[6+j];
        #pragma unroll
        for (int n = 0; n < NT; ++n) {
            float fx = (float)(n % 3) - 1.f;
            float fy = (float)(n / 3) - 1.f;
            float qx = Hm[0]*fx + Hm[1]*fy + Hm[2];
            float qy = Hm[3]*fx + Hm[4]*fy + Hm[5];
            float qz = Hm[6]*fx + Hm[7]*fy + Hm[8];
            float ri = 1.f / qz;
            sOffs[tid*NT + n] = make_float2(qx*ri, qy*ri);
        }
    }
    __syncthreads();

    // ---- phase 3: taps (pair base + slot weights, clamp folded into weights)
    {
        int mny = HN-1, mxy = 0, mnx = WN-1, mxx = 0;
        for (int e = tid; e < 64*NT; e += 256) {
            int pix = e / NT, n = e - pix*NT;
            float2 off = sOffs[e];
            float px = (float)(w0 + pix) + off.x;
            float py = (float)hi + off.y;
            float x0f = floorf(px), y0f = floorf(py);
            float fx = px - x0f,    fy = py - y0f;
            int ix0 = (int)x0f, iy0 = (int)y0f;
            int bx = min(max(ix0, 0), WN-2);
            int by = min(max(iy0, 0), HN-2);
            float wx0 = 1.f - fx, wx1 = fx;
            float wy0 = 1.f - fy, wy1 = fy;
            // slot weights: value for position x0 (if ==bx or bx+1), x1 likewise
            float sxL = (ix0   == bx   ? wx0 : 0.f) + (ix0+1 == bx   ? wx1 : 0.f);
            float sxR = (ix0   == bx+1 ? wx0 : 0.f) + (ix0+1 == bx+1 ? wx1 : 0.f);
            float syT = (iy0   == by   ? wy0 : 0.f) + (iy0+1 == by   ? wy1 : 0.f);
            float syB = (iy0   == by+1 ? wy0 : 0.f) + (iy0+1 == by+1 ? wy1 : 0.f);
            tapP[e] = by*256 + bx;
            tapW[e] = make_float4(syT*sxL, syT*sxR, syB*sxL, syB*sxR);
            mny = min(mny, by); mxy = max(mxy, by);
            mnx = min(mnx, bx); mxx = max(mxx, bx);
        }
        atomicMin(&sB[0], mny); atomicMax(&sB[1], mxy);
        atomicMin(&sB[2], mnx); atomicMax(&sB[3], mxx);
    }
    __syncthreads();

    const int ymin  = sB[0], xmin = sB[2];
    const int rowsN = sB[1] + 2 - ymin;      // includes by+1 row
    const int colsN = sB[3] + 2 - xmin;      // includes bx+1 col
    const bool fits = (rowsN <= R_MAX) && (colsN <= C_W);   // block-uniform
    const int bias  = ymin*C_W + xmin;

    // ---- phase 4: stage window into LDS (coalesced from L2)
    if (fits) {
        const int base_g = ymin*WN + xmin;
        for (int i = tid; i < SX_DWORDS; i += 256) {
            int col = i % C_W;
            int t   = i / C_W;
            int row = t % R_MAX;
            int ch  = t / R_MAX;
            if (row < rowsN && col < colsN)
                sx[i] = xb[(size_t)ch*HWN + base_g + row*WN + col];
        }
    }

    const int lane = tid & 63;
    const int g    = tid >> 6;           // wave id 0..3
    const int q    = lane >> 4;
    const int m15  = lane & 15;
    const int mpix = g*16 + m15;

    floatx4 acc[4];
    #pragma unroll
    for (int f = 0; f < 4; ++f) acc[f] = (floatx4){0.f,0.f,0.f,0.f};

    // ---- phase 5: 9 x (LDS bilinear gather -> bf16 tile -> MFMA)
    for (int n = 0; n < NT; ++n) {
        __syncthreads();                 // staging done / sT reusable
        {
            int e = lane*NT + n;
            int p = tapP[e];
            float4 tw = tapW[e];
            unsigned int packed[8];
            if (fits) {
                int rel = (p >> 8)*C_W + (p & 255) - bias;
                const float* base = sx + g*16*RC + rel;
                #pragma unroll
                for (int jj = 0; jj < 8; ++jj) {
                    const float* p0 = base + (2*jj)*RC;
                    float v0 = tw.x*p0[0] + tw.y*p0[1]
                             + tw.z*p0[C_W] + tw.w*p0[C_W+1];
                    const float* p1 = p0 + RC;
                    float v1 = tw.x*p1[0] + tw.y*p1[1]
                             + tw.z*p1[C_W] + tw.w*p1[C_W+1];
                    packed[jj] = (unsigned int)f2bf(v0)
                               | ((unsigned int)f2bf(v1) << 16);
                }
            } else {
                int a = (p >> 8)*WN + (p & 255);
                const float* basep = xb + (size_t)(g*16)*HWN + a;
                #pragma unroll
                for (int jj = 0; jj < 8; ++jj) {
                    const float* p0 = basep + (size_t)(2*jj)*HWN;
                    float v0 = tw.x*p0[0] + tw.y*p0[1]
                             + tw.z*p0[WN] + tw.w*p0[WN+1];
                    const float* p1 = p0 + HWN;
                    float v1 = tw.x*p1[0] + tw.y*p1[1]
                             + tw.z*p1[WN] + tw.w*p1[WN+1];
                    packed[jj] = (unsigned int)f2bf(v0)
                               | ((unsigned int)f2bf(v1) << 16);
                }
            }
            int4* dst = (int4*)&sT[lane*72 + g*16];
            dst[0] = make_int4(packed[0],packed[1],packed[2],packed[3]);
            dst[1] = make_int4(packed[4],packed[5],packed[6],packed[7]);
        }
        __syncthreads();

        #pragma unroll
        for (int k0 = 0; k0 < 64; k0 += 32) {
            bf16x8 a = *(const bf16x8*)&sT[mpix*72 + k0 + q*8];
            #pragma unroll
            for (int f = 0; f < 4; ++f) {
                bf16x8 bfr = *(const bf16x8*)&wbf[((size_t)(n*ON + f*16 + m15))*CN + k0 + q*8];
                acc[f] = __builtin_amdgcn_mfma_f32_16x16x32_bf16(a, bfr, acc[f], 0, 0, 0);
            }
        }
    }

    // ---- epilogue: transpose through LDS (over dead sx) for coalesced stores
    __syncthreads();
    float* tr = (float*)lds;             // [64 o][72 pix]
    #pragma unroll
    for (int f = 0; f < 4; ++f) {
        int o = f*16 + m15;
        #pragma unroll
        for (int r = 0; r < 4; ++r) {
            int pix = g*16 + q*4 + r;    // C/D layout: row=(lane>>4)*4+reg
            tr[o*72 + pix] = acc[f][r];
        }
    }
    __syncthreads();
    const int og = tid >> 6;
    float* ob = out + (((size_t)bi*ON)*HN + hi)*WN + w0;
    #pragma unroll
    for (int j = 0; j < 16; ++j) {
        int o = og*16 + j;
        ob[(size_t)o*HWN + lane] = tr[o*72 + lane];
    }
}

// ---------------------------------------------------------------------------
extern "C" void kernel_launch(void* const* d_in, const int* in_sizes, int n_in,
                              void* d_out, int out_size, void* d_ws, size_t ws_size,
                              hipStream_t stream) {
    const float* x      = (const float*)d_in[0];
    const float* w_off  = (const float*)d_in[1];
    const float* w_conv = (const float*)d_in[2];
    const float* P      = (const float*)d_in[3];
    const float* d      = (const float*)d_in[4];
    const float* Pinv   = (const float*)d_in[5];
    float* out = (float*)d_out;

    unsigned short* wbf = (unsigned short*)d_ws;   // 73728 B

    wbf_kernel<<<144, 256, 0, stream>>>(w_conv, wbf);
    fused_deform<<<1024, 256, 0, stream>>>(x, w_off, P, d, Pinv, wbf, out);
}

// Round 3
// 147.543 us; speedup vs baseline: 1.9454x; 1.9454x over previous
//
#include <hip/hip_runtime.h>
#include <hip/hip_bf16.h>

#define BN 4
#define CN 64
#define ON 64
#define HN 128
#define WN 128
#define HWN (HN*WN)
#define NT 9

typedef __attribute__((ext_vector_type(8))) short bf16x8;
typedef __attribute__((ext_vector_type(4))) float floatx4;

static __device__ __forceinline__ unsigned short f2bf(float f) {
    unsigned int u = __builtin_bit_cast(unsigned int, f);
    u += 0x7fffu + ((u >> 16) & 1u);   // RNE
    return (unsigned short)(u >> 16);
}

// XCD-aware swizzle for 1024 blocks: XCD k owns works [k*128, k*128+128)
// = 64 consecutive rows of one image (~2.1MB slice < 4MB L2/XCD).
static __device__ __forceinline__ int swz_work(int b) {
    return ((b & 7) << 7) | (b >> 3);
}

// ---------------------------------------------------------------------------
// Kernel T: x (B,C,H,W) f32 -> xT (B,H,W,C) f32  (channel-contiguous).
// One block = 64 pixels (half-row) x 64 channels, LDS transpose.
// ---------------------------------------------------------------------------
__global__ __launch_bounds__(256) void transpose_kernel(
    const float* __restrict__ x, float* __restrict__ xT)
{
    __shared__ float ls[64][65];
    const int tid   = threadIdx.x;
    const int work  = swz_work(blockIdx.x);
    const int pbase = work << 6;
    const int bi    = pbase >> 14;
    const int poff  = pbase & (HWN-1);
    const float* xb = x + (size_t)bi*CN*HWN + poff;
    const int lane = tid & 63, g = tid >> 6;

    #pragma unroll
    for (int k = 0; k < 16; ++k) {
        int c = g*16 + k;
        ls[c][lane] = xb[(size_t)c*HWN + lane];   // coalesced 256B per instr
    }
    __syncthreads();

    float4* dst = (float4*)(xT + (size_t)pbase*CN);
    #pragma unroll
    for (int j = 0; j < 4; ++j) {
        int f4 = j*256 + tid;          // 0..1023 float4s
        int p  = f4 >> 4;
        int c4 = (f4 & 15)*4;
        dst[f4] = make_float4(ls[c4][p], ls[c4+1][p], ls[c4+2][p], ls[c4+3][p]);
    }
}

// ---------------------------------------------------------------------------
// Kernel A (unchanged from R1): lie-weight conv -> Hom -> 9 offsets; builds wbf.
// ---------------------------------------------------------------------------
__global__ __launch_bounds__(256) void offsets_kernel(
    const float* __restrict__ x, const float* __restrict__ w_off,
    const float* __restrict__ w_conv,
    const float* __restrict__ P, const float* __restrict__ d,
    const float* __restrict__ Pinv,
    float2* __restrict__ offs, unsigned short* __restrict__ wbf)
{
    const int tid = threadIdx.x;
    __shared__ float swoff[CN*NT];
    __shared__ float sred[4][64];
    __shared__ float sHm[64][10];

    for (int i = tid; i < CN*NT; i += 256) swoff[i] = w_off[i];

    int gid = blockIdx.x * 256 + tid;
    if (gid < ON*CN*NT) {
        int o   = gid / (CN*NT);
        int rem = gid - o*(CN*NT);
        int c   = rem / NT;
        int n   = rem - c*NT;
        wbf[(n*ON + o)*CN + c] = f2bf(w_conv[gid]);
    }

    const int work  = swz_work(blockIdx.x);
    const int pbase = work << 6;
    const int pix   = tid & 63;
    const int cg    = tid >> 6;
    const int p     = pbase + pix;
    const int wi    = p & (WN-1);
    const int hi    = (p >> 7) & (HN-1);
    const int bi    = p >> 14;
    const float* xb   = x + (size_t)bi*CN*HWN + (size_t)(cg*16)*HWN;
    const float* swc0 = &swoff[cg*16*NT];

    __syncthreads();

    float accv = 0.f;
    #pragma unroll
    for (int ky = 0; ky < 3; ++ky) {
        int yy = hi + ky - 1;
        #pragma unroll
        for (int kx = 0; kx < 3; ++kx) {
            int xx = wi + kx - 1;
            bool v  = (yy >= 0) && (yy < HN) && (xx >= 0) && (xx < WN);
            float m = v ? 1.f : 0.f;
            int a   = v ? (yy*WN + xx) : 0;
            const float* swc = swc0 + (ky*3 + kx);
            float t0 = 0.f, t1 = 0.f, t2 = 0.f, t3 = 0.f;
            #pragma unroll
            for (int c = 0; c < 16; c += 4) {
                t0 = fmaf(xb[(size_t)(c+0)*HWN + a], swc[(c+0)*NT], t0);
                t1 = fmaf(xb[(size_t)(c+1)*HWN + a], swc[(c+1)*NT], t1);
                t2 = fmaf(xb[(size_t)(c+2)*HWN + a], swc[(c+2)*NT], t2);
                t3 = fmaf(xb[(size_t)(c+3)*HWN + a], swc[(c+3)*NT], t3);
            }
            accv = fmaf(m, (t0+t1)+(t2+t3), accv);
        }
    }
    sred[cg][pix] = accv;
    __syncthreads();

    if (tid < 64) {
        float raw = (sred[0][tid]+sred[1][tid]) + (sred[2][tid]+sred[3][tid]);
        float lw  = fminf(fmaxf(raw + 0.5f, 0.f), 1.f);
        float pw[3];
        #pragma unroll
        for (int k = 0; k < 3; ++k) pw[k] = exp2f(lw * log2f(d[k]));
        #pragma unroll
        for (int i = 0; i < 3; ++i)
            #pragma unroll
            for (int j = 0; j < 3; ++j)
                sHm[tid][i*3+j] = P[i*3+0]*pw[0]*Pinv[0+j]
                                + P[i*3+1]*pw[1]*Pinv[3+j]
                                + P[i*3+2]*pw[2]*Pinv[6+j];
    }
    __syncthreads();

    for (int e = tid; e < 64*NT; e += 256) {
        int pp = e / NT, n = e - pp*NT;
        float fx = (float)(n % 3) - 1.f;
        float fy = (float)(n / 3) - 1.f;
        float qx = sHm[pp][0]*fx + sHm[pp][1]*fy + sHm[pp][2];
        float qy = sHm[pp][3]*fx + sHm[pp][4]*fy + sHm[pp][5];
        float qz = sHm[pp][6]*fx + sHm[pp][7]*fy + sHm[pp][8];
        float ri = 1.f / qz;
        offs[(size_t)(pbase+pp)*NT + n] = make_float2(qx*ri, qy*ri);
    }
}

// ---------------------------------------------------------------------------
// Kernel B (new): gather from channel-contiguous xT with float4 loads.
// Wave g owns pixels g*16..g*16+15 -> sT rows are wave-private -> NO barriers
// in the n-loop. Taps use R2's verified clamp-folded pair-base encoding.
// ---------------------------------------------------------------------------
#define LDSB 20736   // tapB 2304 | tapW 9216 | sT 9216 (64 x 72 bf16)

__global__ __launch_bounds__(256) void deform_xt(
    const float* __restrict__ xT, const float2* __restrict__ offs,
    const unsigned short* __restrict__ wbf, float* __restrict__ out)
{
    __shared__ __align__(16) char lds[LDSB];
    int*            tapB = (int*)lds;                       // [576] dword base
    float4*         tapW = (float4*)(lds + 2304);           // [576]
    unsigned short* sT   = (unsigned short*)(lds + 11520);  // [64][72]

    const int tid   = threadIdx.x;
    const int work  = swz_work(blockIdx.x);
    const int pbase = work << 6;
    const int w0    = pbase & (WN-1);
    const int hi    = (pbase >> 7) & (HN-1);
    const int bi    = pbase >> 14;
    const float* xTb = xT + (size_t)bi * HWN * CN;

    // ---- taps: pair-base (by,bx in [0,126]) + slot weights, clamp folded in
    for (int e = tid; e < 64*NT; e += 256) {
        int pix = e / NT, n = e - pix*NT;
        float2 off = offs[(size_t)(pbase + pix)*NT + n];
        float px = (float)(w0 + pix) + off.x;
        float py = (float)hi + off.y;
        float x0f = floorf(px), y0f = floorf(py);
        float fx = px - x0f,    fy = py - y0f;
        int ix0 = (int)x0f, iy0 = (int)y0f;
        int bx = min(max(ix0, 0), WN-2);
        int by = min(max(iy0, 0), HN-2);
        float wx0 = 1.f - fx, wx1 = fx;
        float wy0 = 1.f - fy, wy1 = fy;
        float sxL = (ix0   == bx   ? wx0 : 0.f) + (ix0+1 == bx   ? wx1 : 0.f);
        float sxR = (ix0   == bx+1 ? wx0 : 0.f) + (ix0+1 == bx+1 ? wx1 : 0.f);
        float syT = (iy0   == by   ? wy0 : 0.f) + (iy0+1 == by   ? wy1 : 0.f);
        float syB = (iy0   == by+1 ? wy0 : 0.f) + (iy0+1 == by+1 ? wy1 : 0.f);
        tapB[e] = (by*WN + bx)*CN;
        tapW[e] = make_float4(syT*sxL, syT*sxR, syB*sxL, syB*sxR);
    }
    __syncthreads();                      // taps ready; read-only hereafter

    const int lane = tid & 63;
    const int g    = tid >> 6;
    const int q    = lane >> 4;
    const int m15  = lane & 15;
    const int mpix = g*16 + m15;
    const int psub = lane >> 4;           // pixel-subgroup 0..3
    const int k4   = (lane & 15)*4;       // channel quad

    floatx4 acc[4];
    #pragma unroll
    for (int f = 0; f < 4; ++f) acc[f] = (floatx4){0.f,0.f,0.f,0.f};

    for (int n = 0; n < NT; ++n) {
        // gather: wave g fills sT rows g*16..g*16+15 (wave-private, no barrier)
        #pragma unroll 2
        for (int s = 0; s < 4; ++s) {
            int p = g*16 + s*4 + psub;
            int e = p*NT + n;
            int tb = tapB[e];
            float4 tw = tapW[e];
            const float* A = xTb + tb + k4;
            float4 v00 = *(const float4*)A;
            float4 v01 = *(const float4*)(A + CN);
            float4 v10 = *(const float4*)(A + WN*CN);
            float4 v11 = *(const float4*)(A + WN*CN + CN);
            float rx = fmaf(tw.x,v00.x, fmaf(tw.y,v01.x, fmaf(tw.z,v10.x, tw.w*v11.x)));
            float ry = fmaf(tw.x,v00.y, fmaf(tw.y,v01.y, fmaf(tw.z,v10.y, tw.w*v11.y)));
            float rz = fmaf(tw.x,v00.z, fmaf(tw.y,v01.z, fmaf(tw.z,v10.z, tw.w*v11.z)));
            float rw = fmaf(tw.x,v00.w, fmaf(tw.y,v01.w, fmaf(tw.z,v10.w, tw.w*v11.w)));
            unsigned int u0 = (unsigned int)f2bf(rx) | ((unsigned int)f2bf(ry) << 16);
            unsigned int u1 = (unsigned int)f2bf(rz) | ((unsigned int)f2bf(rw) << 16);
            *(uint2*)&sT[p*72 + k4] = make_uint2(u0, u1);
        }
        // MFMA on this wave's own rows (compiler inserts lgkmcnt for sT dep)
        #pragma unroll
        for (int k0 = 0; k0 < 64; k0 += 32) {
            bf16x8 a = *(const bf16x8*)&sT[mpix*72 + k0 + q*8];
            #pragma unroll
            for (int f = 0; f < 4; ++f) {
                bf16x8 bfr = *(const bf16x8*)&wbf[((size_t)(n*ON + f*16 + m15))*CN + k0 + q*8];
                acc[f] = __builtin_amdgcn_mfma_f32_16x16x32_bf16(a, bfr, acc[f], 0, 0, 0);
            }
        }
    }

    // ---- epilogue: transpose through LDS for coalesced stores
    __syncthreads();
    float* tr = (float*)lds;             // [64 o][72 pix] over dead tap/sT
    #pragma unroll
    for (int f = 0; f < 4; ++f) {
        int o = f*16 + m15;
        #pragma unroll
        for (int r = 0; r < 4; ++r) {
            int pix = g*16 + q*4 + r;    // C/D layout: row=(lane>>4)*4+reg
            tr[o*72 + pix] = acc[f][r];
        }
    }
    __syncthreads();
    const int og = tid >> 6;
    float* ob = out + (((size_t)bi*ON)*HN + hi)*WN + w0;
    #pragma unroll
    for (int j = 0; j < 16; ++j) {
        int o = og*16 + j;
        ob[(size_t)o*HWN + lane] = tr[o*72 + lane];
    }
}

// ---------------------------------------------------------------------------
// Legacy deform (R1, gather from x) — fallback if workspace too small for xT.
// ---------------------------------------------------------------------------
#define LDS_BYTES 27648

__global__ __launch_bounds__(256) void deform_legacy(
    const float* __restrict__ x, const float2* __restrict__ offs,
    const unsigned short* __restrict__ wbf, float* __restrict__ out)
{
    __shared__ char lds[LDS_BYTES];
    int4*   tapA = (int4*)lds;
    float4* tapW = (float4*)(lds + 9216);
    unsigned short* sT = (unsigned short*)(lds + 18432);

    const int tid   = threadIdx.x;
    const int work  = swz_work(blockIdx.x);
    const int pbase = work << 6;
    const int w0    = pbase & (WN-1);
    const int hi    = (pbase >> 7) & (HN-1);
    const int bi    = pbase >> 14;

    for (int e = tid; e < 64*NT; e += 256) {
        int pix = e / NT, n = e - pix*NT;
        float2 off = offs[(pbase + pix)*NT + n];
        float px = (float)(w0 + pix) + off.x;
        float py = (float)hi + off.y;
        float x0f = floorf(px), y0f = floorf(py);
        float fx = px - x0f,    fy = py - y0f;
        int ix0 = (int)x0f, iy0 = (int)y0f;
        int ix1 = ix0 + 1,  iy1 = iy0 + 1;
        float vx0 = (ix0 >= 0 && ix0 < WN) ? 1.f : 0.f;
        float vx1 = (ix1 >= 0 && ix1 < WN) ? 1.f : 0.f;
        float vy0 = (iy0 >= 0 && iy0 < HN) ? 1.f : 0.f;
        float vy1 = (iy1 >= 0 && iy1 < HN) ? 1.f : 0.f;
        int x0c = min(max(ix0,0),WN-1), x1c = min(max(ix1,0),WN-1);
        int y0c = min(max(iy0,0),HN-1), y1c = min(max(iy1,0),HN-1);
        tapA[e] = make_int4(y0c*WN+x0c, y0c*WN+x1c, y1c*WN+x0c, y1c*WN+x1c);
        tapW[e] = make_float4((1.f-fy)*(1.f-fx)*vy0*vx0, (1.f-fy)*fx*vy0*vx1,
                              fy*(1.f-fx)*vy1*vx0,       fy*fx*vy1*vx1);
    }

    const int lane = tid & 63;
    const int g    = tid >> 6;
    const int q    = lane >> 4;
    const int m15  = lane & 15;
    const int mpix = g*16 + m15;
    const float* xb = x + (size_t)bi * CN * HWN;

    floatx4 acc[4];
    #pragma unroll
    for (int f = 0; f < 4; ++f) acc[f] = (floatx4){0.f,0.f,0.f,0.f};

    for (int n = 0; n < NT; ++n) {
        __syncthreads();
        {
            int pix = lane;
            int4   ta = tapA[pix*NT + n];
            float4 tw = tapW[pix*NT + n];
            const float* pc = xb + (g*16)*HWN;
            unsigned int packed[8];
            #pragma unroll
            for (int jj = 0; jj < 8; ++jj) {
                const float* p0 = pc + (2*jj)*HWN;
                float v0 = tw.x*p0[ta.x] + tw.y*p0[ta.y]
                         + tw.z*p0[ta.z] + tw.w*p0[ta.w];
                const float* p1 = p0 + HWN;
                float v1 = tw.x*p1[ta.x] + tw.y*p1[ta.y]
                         + tw.z*p1[ta.z] + tw.w*p1[ta.w];
                packed[jj] = (unsigned int)f2bf(v0)
                           | ((unsigned int)f2bf(v1) << 16);
            }
            int4* dst = (int4*)&sT[pix*72 + g*16];
            dst[0] = make_int4(packed[0],packed[1],packed[2],packed[3]);
            dst[1] = make_int4(packed[4],packed[5],packed[6],packed[7]);
        }
        __syncthreads();

        #pragma unroll
        for (int k0 = 0; k0 < 64; k0 += 32) {
            bf16x8 a = *(const bf16x8*)&sT[mpix*72 + k0 + q*8];
            #pragma unroll
            for (int f = 0; f < 4; ++f) {
                bf16x8 bfr = *(const bf16x8*)&wbf[((size_t)(n*ON + f*16 + m15))*CN + k0 + q*8];
                acc[f] = __builtin_amdgcn_mfma_f32_16x16x32_bf16(a, bfr, acc[f], 0, 0, 0);
            }
        }
    }

    __syncthreads();
    float* tr = (float*)lds;
    #pragma unroll
    for (int f = 0; f < 4; ++f) {
        int o = f*16 + m15;
        #pragma unroll
        for (int r = 0; r < 4; ++r) {
            int pix = g*16 + q*4 + r;
            tr[o*72 + pix] = acc[f][r];
        }
    }
    __syncthreads();
    const int og = tid >> 6;
    float* ob = out + (((size_t)bi*ON)*HN + hi)*WN + w0;
    #pragma unroll
    for (int j = 0; j < 16; ++j) {
        int o = og*16 + j;
        ob[(size_t)o*HWN + lane] = tr[o*72 + lane];
    }
}

// ---------------------------------------------------------------------------
extern "C" void kernel_launch(void* const* d_in, const int* in_sizes, int n_in,
                              void* d_out, int out_size, void* d_ws, size_t ws_size,
                              hipStream_t stream) {
    const float* x      = (const float*)d_in[0];
    const float* w_off  = (const float*)d_in[1];
    const float* w_conv = (const float*)d_in[2];
    const float* P      = (const float*)d_in[3];
    const float* d      = (const float*)d_in[4];
    const float* Pinv   = (const float*)d_in[5];
    float* out = (float*)d_out;

    const size_t XT_BYTES   = (size_t)BN*HN*WN*CN*4;   // 16777216
    const size_t OFFS_BYTES = (size_t)BN*HWN*NT*8;     // 4718592
    const size_t WBF_BYTES  = (size_t)ON*CN*NT*2;      // 73728

    if (ws_size >= XT_BYTES + OFFS_BYTES + WBF_BYTES) {
        float*  xT  = (float*)d_ws;
        float2* offs = (float2*)((char*)d_ws + XT_BYTES);
        unsigned short* wbf = (unsigned short*)((char*)d_ws + XT_BYTES + OFFS_BYTES);
        transpose_kernel<<<1024, 256, 0, stream>>>(x, xT);
        offsets_kernel<<<1024, 256, 0, stream>>>(x, w_off, w_conv, P, d, Pinv, offs, wbf);
        deform_xt<<<1024, 256, 0, stream>>>(xT, offs, wbf, out);
    } else {
        float2* offs = (float2*)d_ws;
        unsigned short* wbf = (unsigned short*)((char*)d_ws + OFFS_BYTES);
        offsets_kernel<<<1024, 256, 0, stream>>>(x, w_off, w_conv, P, d, Pinv, offs, wbf);
        deform_legacy<<<1024, 256, 0, stream>>>(x, offs, wbf, out);
    }
}